// Round 3
// baseline (269.432 us; speedup 1.0000x reference)
//
#include <hip/hip_runtime.h>
#include <math.h>

typedef float vfloat4 __attribute__((ext_vector_type(4)));

// Fill V = I. Layout is derived on-device: N is read from d_in[6]; the row
// stride in floats is out_size / N. stride == 2N -> interleaved complex rows
// (re,im pairs, diag 1.0 at float offset 2*row). stride == N -> real-only
// matrix (diag at offset row). Unified: diag offset = row * (stride/N).
// One float4 (16B) nontemporal store per thread, fully coalesced 1D.
__global__ void fill_identity_kernel(vfloat4* __restrict__ out, int out_size,
                                     const int* __restrict__ Np) {
    const int n = Np[0];                 // wave-uniform scalar load
    const int stride = out_size / n;     // floats per row (N or 2N)
    const int mult = stride / n;         // 1 (real) or 2 (complex interleaved)
    const int ls = 31 - __clz(stride);   // stride is a power of two (N=8192)

    const size_t f = ((size_t)blockIdx.x * blockDim.x + threadIdx.x) * 4;
    if (f >= (size_t)out_size) return;

    const int row = (int)(f >> ls);
    const int o = (int)(f & (size_t)(stride - 1));  // float offset within row

    vfloat4 v = {0.f, 0.f, 0.f, 0.f};
    const int k = row * mult - o;        // position of this row's 1.0 in this float4
    if (k >= 0 && k < 4) v[k] = 1.0f;

    __builtin_nontemporal_store(v, out + (f >> 2));
}

// Single-thread epilogue: closed-form exp(i*H) for the 2x2 Hermitian block.
__global__ void patch_block_kernel(float* __restrict__ out, int out_size,
                                   const float* __restrict__ bii,
                                   const float* __restrict__ bjj,
                                   const float* __restrict__ bij_real,
                                   const float* __restrict__ bij_img,
                                   const int* __restrict__ conn_i,
                                   const int* __restrict__ conn_j,
                                   const int* __restrict__ Np) {
    if (threadIdx.x != 0 || blockIdx.x != 0) return;

    const int n = Np[0];
    const int stride = out_size / n;
    const int mult = stride / n;  // 1 or 2

    const float a  = bii[0];
    const float b  = bjj[0];
    const float cr = bij_real[0];
    const float ci = bij_img[0];

    const float t = 0.5f * (a + b);
    const float d = 0.5f * (a - b);
    const float r = sqrtf(d * d + cr * cr + ci * ci);
    const float sinc = (r > 0.f) ? (sinf(r) / r) : 1.0f;
    const float cosr = cosf(r);
    const float pr = cosf(t);   // phase = exp(i t)
    const float pi = sinf(t);

    const float sd = sinc * d;
    const float eii_r = pr * cosr - pi * sd;
    const float eii_i = pr * sd + pi * cosr;
    const float ejj_r = pr * cosr + pi * sd;
    const float ejj_i = -pr * sd + pi * cosr;
    const float sc_r = -sinc * ci;
    const float sc_i = sinc * cr;
    const float eij_r = pr * sc_r - pi * sc_i;
    const float eij_i = pr * sc_i + pi * sc_r;
    const float sj_r = sinc * ci;
    const float sj_i = sinc * cr;
    const float eji_r = pr * sj_r - pi * sj_i;
    const float eji_i = pr * sj_i + pi * sj_r;

    const int i = conn_i[0];
    const int j = conn_j[0];

    if (mult == 2) {  // interleaved complex
        size_t idx;
        idx = (size_t)i * stride + 2 * (size_t)i; out[idx] = eii_r; out[idx + 1] = eii_i;
        idx = (size_t)j * stride + 2 * (size_t)j; out[idx] = ejj_r; out[idx + 1] = ejj_i;
        idx = (size_t)i * stride + 2 * (size_t)j; out[idx] = eij_r; out[idx + 1] = eij_i;
        idx = (size_t)j * stride + 2 * (size_t)i; out[idx] = eji_r; out[idx + 1] = eji_i;
    } else {          // real-only matrix
        out[(size_t)i * stride + i] = eii_r;
        out[(size_t)j * stride + j] = ejj_r;
        out[(size_t)i * stride + j] = eij_r;
        out[(size_t)j * stride + i] = eji_r;
    }
}

extern "C" void kernel_launch(void* const* d_in, const int* in_sizes, int n_in,
                              void* d_out, int out_size, void* d_ws, size_t ws_size,
                              hipStream_t stream) {
    const float* bii      = (const float*)d_in[0];
    const float* bjj      = (const float*)d_in[1];
    const float* bij_real = (const float*)d_in[2];
    const float* bij_img  = (const float*)d_in[3];
    const int*   conn_i   = (const int*)d_in[4];
    const int*   conn_j   = (const int*)d_in[5];
    const int*   Np       = (const int*)d_in[6];

    float* out = (float*)d_out;

    // One float4 per thread over the whole buffer; out_size divisible by 4.
    const int n_f4 = out_size >> 2;
    const int blocks = (n_f4 + 255) / 256;
    fill_identity_kernel<<<dim3(blocks), dim3(256), 0, stream>>>(
        (vfloat4*)out, out_size, Np);

    patch_block_kernel<<<dim3(1), dim3(64), 0, stream>>>(
        out, out_size, bii, bjj, bij_real, bij_img, conn_i, conn_j, Np);
}